// Round 19
// baseline (116.659 us; speedup 1.0000x reference)
//
#include <hip/hip_runtime.h>
#include <math.h>

#define CCH 4096
#define SP 891
#define NSL 32768

typedef __attribute__((ext_vector_type(8))) short short8;
typedef __attribute__((ext_vector_type(4))) float f32x4;

__device__ __forceinline__ unsigned int pack_bf2(float a, float b) {
  unsigned int ua = __builtin_bit_cast(unsigned int, a);
  unsigned int ub = __builtin_bit_cast(unsigned int, b);
  ua = (ua + 0x7fffu + ((ua >> 16) & 1u)) >> 16;
  ub = (ub + 0x7fffu + ((ub >> 16) & 1u)) >> 16;
  return ua | (ub << 16);
}

// ---------- setup: members + rowSid + rowC + cnt/off (80 blocks x 64) ----------
__global__ void k_setup(const int* __restrict__ im0, const int* __restrict__ im1,
                        int* cnt0, int* off0, int* cnt1, int* off1,
                        int* mem0, int* mem1, int* rs0, int* rs1,
                        int* rowC0, int* rowC1) {
  int cb = blockIdx.x;
  int level = (cb >= 64) ? 1 : 0;
  int c = level ? cb - 64 : cb;
  const int* im = level ? im1 : im0;
  int* members = level ? mem1 : mem0;
  int* rs = level ? rs1 : rs0;
  int* rowC = level ? rowC1 : rowC0;
  int lane = threadIdx.x;  // 64
  int lt = 0;
  for (int ch = lane; ch < CCH; ch += 64) lt += (im[ch] < c) ? 1 : 0;
  for (int o = 32; o; o >>= 1) lt += __shfl_xor(lt, o, 64);
  int base = lt;
  int cnt = 0;
  for (int chunk = 0; chunk < CCH; chunk += 64) {
    int ch = chunk + lane;
    bool m = (im[ch] == c);
    unsigned long long mk = __ballot(m);
    int pos = __popcll(mk & ((1ull << lane) - 1ull));
    if (m) members[base + cnt + pos] = ch;
    cnt += __popcll(mk);
  }
  int n = cnt;
  if (lane == 0) {
    if (level) { cnt1[c] = n; off1[c] = base; }
    else       { cnt0[c] = n; off0[c] = base; }
  }
  __syncthreads();
  for (int r = lane; r < n; r += 64) {
    rowC[base + r] = c;
    #pragma unroll
    for (int q = 0; q < 8; q++) {
      int p = 8 * r + q;
      int b = p / n, j = p - b * n;
      rs[(size_t)(base + r) * 8 + q] = b * CCH + members[base + j];
    }
  }
}

// ---------- pack rep slices into fragment-major bf16 tables (B operands) ----------
__global__ void k_brep(const float* __restrict__ X,
    const int* __restrict__ off0, const int* __restrict__ off1,
    const int* __restrict__ rs0, const int* __restrict__ rs1,
    uint4* __restrict__ Bfrag0, uint4* __restrict__ Bfrag1) {
  int gid = blockIdx.x * 4 + (threadIdx.x >> 6);  // 0..39
  int l = threadIdx.x & 63;
  int lrow = l & 15, hi = l >> 4;
  int level = (gid >= 32) ? 1 : 0;
  int q = level ? (gid - 32) : (gid >> 2);
  int ct = level ? 0 : (gid & 3);
  int cc = ct * 16 + lrow;
  int base = level ? off1[cc] : off0[cc];
  int sid = (level ? rs1 : rs0)[(size_t)base * 8 + q];
  const float* ap = X + (size_t)sid * SP + hi * 8;
  uint4* dst = (level ? Bfrag1 + (size_t)(q * 28) * 64
                      : Bfrag0 + (size_t)((q * 4 + ct) * 28) * 64) + l;
  #pragma unroll 3
  for (int kc = 0; kc < 27; kc++) {
    float4 fa0 = *(const float4*)(ap + kc * 32);
    float4 fa1 = *(const float4*)(ap + kc * 32 + 4);
    uint4 ua;
    ua.x = pack_bf2(fa0.x, fa0.y); ua.y = pack_bf2(fa0.z, fa0.w);
    ua.z = pack_bf2(fa1.x, fa1.y); ua.w = pack_bf2(fa1.z, fa1.w);
    dst[kc * 64] = ua;
  }
  {
    float4 fa0, fa1;
    if (hi == 3) {
      fa0 = make_float4(ap[864], ap[865], ap[866], 0.f);
      fa1 = make_float4(0.f, 0.f, 0.f, 0.f);
    } else {
      fa0 = *(const float4*)(ap + 864);
      fa1 = *(const float4*)(ap + 868);
    }
    uint4 ua;
    ua.x = pack_bf2(fa0.x, fa0.y); ua.y = pack_bf2(fa0.z, fa0.w);
    ua.z = pack_bf2(fa1.x, fa1.y); ua.w = pack_bf2(fa1.z, fa1.w);
    dst[27 * 64] = ua;
  }
}

// ---------- fused transpose-in-LDS MFMA GEMM, both levels (grid 512 x 8) ----------
__global__ __launch_bounds__(256) void k_gemm_all(const float* __restrict__ X,
    const int* __restrict__ rs0, const int* __restrict__ rs1,
    const uint4* __restrict__ Bfrag0, const uint4* __restrict__ Bfrag1,
    float* __restrict__ P8_0, float* __restrict__ P8_1, float* __restrict__ sn2) {
  __shared__ __align__(16) unsigned short T[16 * 896];   // 28 KB
  __shared__ int s_sid[16];
  const int q = blockIdx.y, tid = threadIdx.x;
  const int lev = blockIdx.x >> 8;
  const int rt = blockIdx.x & 255;
  const int* rs = lev ? rs1 : rs0;
  if (tid < 16) s_sid[tid] = rs[(size_t)(rt * 16 + tid) * 8 + q];
  __syncthreads();
  // ---- phase 1: load + pack + swizzled LDS transpose ----
  const int i = tid >> 4, j = tid & 15;
  const float* sp = X + (size_t)s_sid[i] * SP;
  char* Ti = (char*)(T + i * 896);
  const int isw = (i & 7) << 4;
  float s2 = 0.f;
  #pragma unroll
  for (int kcc = 0; kcc < 7; kcc++) {
    int cidx = kcc * 16 + j;
    int el = cidx * 8;
    float4 v0, v1;
    if (cidx < 111) {
      v0 = *(const float4*)(sp + el);
      v1 = *(const float4*)(sp + el + 4);
    } else {
      v0 = make_float4(sp[888], sp[889], sp[890], 0.f);
      v1 = make_float4(0.f, 0.f, 0.f, 0.f);
    }
    s2 += v0.x * v0.x + v0.y * v0.y + v0.z * v0.z + v0.w * v0.w
        + v1.x * v1.x + v1.y * v1.y + v1.z * v1.z + v1.w * v1.w;
    uint4 u;
    u.x = pack_bf2(v0.x, v0.y); u.y = pack_bf2(v0.z, v0.w);
    u.z = pack_bf2(v1.x, v1.y); u.w = pack_bf2(v1.z, v1.w);
    *(uint4*)(Ti + ((cidx * 16) ^ isw)) = u;
  }
  if (!lev) {
    s2 += __shfl_xor(s2, 1, 16); s2 += __shfl_xor(s2, 2, 16);
    s2 += __shfl_xor(s2, 4, 16); s2 += __shfl_xor(s2, 8, 16);
    if (j == 0) sn2[s_sid[i]] = s2;
  }
  __syncthreads();
  // ---- phase 3: MFMA ----
  const int l = tid & 63, w = tid >> 6;
  const int lrow = l & 15, hi = l >> 4;
  const char* Abase = (const char*)T + lrow * 1792;
  const int rsw = (lrow & 7) << 4;
  if (!lev) {
    const uint4* bq = Bfrag0 + (size_t)((q * 4 + w) * 28) * 64 + l;
    f32x4 acc = {0.f, 0.f, 0.f, 0.f};
    short8 A0, A1;
    uint4 B0, B1, B2, B3;
    A0 = *(const short8*)(Abase + ((0 * 64 + hi * 16) ^ rsw));
    A1 = *(const short8*)(Abase + ((1 * 64 + hi * 16) ^ rsw));
    B0 = bq[0 * 64]; B1 = bq[1 * 64]; B2 = bq[2 * 64]; B3 = bq[3 * 64];
    #pragma unroll
    for (int kc = 0; kc < 28; kc++) {
      short8 a = (kc & 1) ? A1 : A0;
      uint4 b = (kc & 3) == 0 ? B0 : (kc & 3) == 1 ? B1 : (kc & 3) == 2 ? B2 : B3;
      acc = __builtin_amdgcn_mfma_f32_16x16x32_bf16(a, __builtin_bit_cast(short8, b), acc, 0, 0, 0);
      if (kc + 2 < 28) {
        short8 an = *(const short8*)(Abase + (((kc + 2) * 64 + hi * 16) ^ rsw));
        if (kc & 1) A1 = an; else A0 = an;
      }
      if (kc + 4 < 28) {
        uint4 bn = bq[(kc + 4) * 64];
        switch (kc & 3) { case 0: B0 = bn; break; case 1: B1 = bn; break;
                          case 2: B2 = bn; break; default: B3 = bn; }
      }
    }
    #pragma unroll
    for (int r = 0; r < 4; r++) {
      int row = rt * 16 + hi * 4 + r;
      P8_0[((size_t)q * CCH + row) * 64 + w * 16 + lrow] = acc[r];
    }
  } else {
    const uint4* bq = Bfrag1 + (size_t)(q * 28) * 64 + l;
    f32x4 acc = {0.f, 0.f, 0.f, 0.f};
    #pragma unroll
    for (int kk = 0; kk < 7; kk++) {
      int kc = w * 7 + kk;
      short8 a = *(const short8*)(Abase + ((kc * 64 + hi * 16) ^ rsw));
      uint4 b = bq[kc * 64];
      acc = __builtin_amdgcn_mfma_f32_16x16x32_bf16(a, __builtin_bit_cast(short8, b), acc, 0, 0, 0);
    }
    __syncthreads();
    float4* Tf = (float4*)T;
    Tf[w * 64 + l] = make_float4(acc[0], acc[1], acc[2], acc[3]);
    __syncthreads();
    if (w == 0) {
      float4 v0 = Tf[l], v1 = Tf[64 + l], v2 = Tf[128 + l], v3 = Tf[192 + l];
      float vr[4] = { v0.x + v1.x + v2.x + v3.x, v0.y + v1.y + v2.y + v3.y,
                      v0.z + v1.z + v2.z + v3.z, v0.w + v1.w + v2.w + v3.w };
      #pragma unroll
      for (int r = 0; r < 4; r++) {
        int row = rt * 16 + hi * 4 + r;
        P8_1[((size_t)q * CCH + row) * 16 + lrow] = vr[r];
      }
    }
  }
}

// ---------- fin1: conc numerators (row-parallel, both levels, 256 blocks) ----------
__global__ __launch_bounds__(256) void k_fin1(const float* __restrict__ P8_0,
    const float* __restrict__ P8_1, const float* __restrict__ sn2,
    const int* __restrict__ rs0, const int* __restrict__ rs1,
    const int* __restrict__ off0, const int* __restrict__ off1,
    const int* __restrict__ rowC0, const int* __restrict__ rowC1,
    float* __restrict__ concNum) {
  __shared__ float cl[80];
  int tid = threadIdx.x;
  if (tid < 80) cl[tid] = 0.f;
  __syncthreads();
  int level = blockIdx.x >> 7;
  int rbase = (blockIdx.x & 127) * 32;
  const float* P8 = level ? P8_1 : P8_0;
  const int* rs = level ? rs1 : rs0;
  const int* off = level ? off1 : off0;
  const int* rowC = level ? rowC1 : rowC0;
  int K = level ? 16 : 64;
  int row = rbase + (tid >> 3), q = tid & 7;
  int c = rowC[row];
  float p = P8[((size_t)q * CCH + row) * K + c];
  float rn = sn2[rs[(size_t)row * 8 + q]];
  for (int o = 1; o < 8; o <<= 1) { p += __shfl_xor(p, o, 8); rn += __shfl_xor(rn, o, 8); }
  if (q == 0) {
    int base = off[c];
    if (row != base) {  // row 0 of a cluster contributes exactly 0 (matches ref)
      float rn0 = 0.f;
      for (int qq = 0; qq < 8; qq++) rn0 += sn2[rs[(size_t)base * 8 + qq]];
      float d2 = rn - 2.f * p + rn0;
      float sv = (d2 > 0.f) ? sqrtf(d2) : 0.f;
      atomicAdd(&cl[level * 64 + c], sv);
    }
  }
  __syncthreads();
  if (tid < 80 && cl[tid] != 0.f) atomicAdd(&concNum[tid], cl[tid]);
}

// ---------- fin2: per-row logsumexp + loss accumulation ----------
template<int K>
__global__ __launch_bounds__(256) void k_fin2(const float* __restrict__ P8,
    const int* __restrict__ counts, const int* __restrict__ rowC,
    const float* __restrict__ concNum, int cbase_g,
    float* __restrict__ lossAcc, int lidx) {
  __shared__ float lsum;
  if (threadIdx.x == 0) lsum = 0.f;
  __syncthreads();
  constexpr int RPW = 64 / K;
  int w = threadIdx.x >> 6, lane = threadIdx.x & 63;
  int sub = (K == 64) ? 0 : (lane >> 4);
  int row = blockIdx.x * (4 * RPW) + w * RPW + sub;
  int cc = lane & (K - 1);
  int c = rowC[row];
  int n = counts[c];
  float conc = concNum[cbase_g + c] / ((float)n * logf((float)n + 10.f));
  float invc = 1.f / conc;
  float s = 0.f;
  #pragma unroll
  for (int q = 0; q < 8; q++) s += P8[((size_t)q * CCH + row) * K + cc];
  float lg = s * invc;
  float nomv = __shfl(lg, (lane & ~(K - 1)) + c, 64);
  float m = lg;
  #pragma unroll
  for (int o = K / 2; o; o >>= 1) m = fmaxf(m, __shfl_xor(m, o, K));
  float e = expf(lg - m);
  float se = e;
  #pragma unroll
  for (int o = K / 2; o; o >>= 1) se += __shfl_xor(se, o, K);
  if (cc == 0 && n >= 2) {
    float contrib = (m + logf(se) - nomv) / (float)n;
    atomicAdd(&lsum, contrib);
  }
  __syncthreads();
  if (threadIdx.x == 0) atomicAdd(&lossAcc[lidx], lsum);
}

// ---------- final scalars ----------
__global__ void k_final(const float* __restrict__ lossAcc, float* __restrict__ out) {
  if (threadIdx.x == 0) {
    out[0] = lossAcc[0] / 4096.0f;
    out[1] = lossAcc[1] / 8192.0f;
  }
}

extern "C" void kernel_launch(void* const* d_in, const int* in_sizes, int n_in,
                              void* d_out, int out_size, void* d_ws, size_t ws_size,
                              hipStream_t stream) {
  const float* X = (const float*)d_in[0];
  const int* im0 = (const int*)d_in[1];
  const int* im1 = (const int*)d_in[2];
  float* out = (float*)d_out;

  char* w = (char*)d_ws;
  auto alloc = [&](size_t bytes) -> char* {
    char* p = w; w += (bytes + 255) & ~(size_t)255; return p;
  };
  float* concNum = (float*)alloc((80 + 2) * 4);  // concNum[80] + lossAcc[2]
  float* lossAcc = concNum + 80;
  int*    cnt0  = (int*)alloc(64 * 4);
  int*    off0  = (int*)alloc(64 * 4);
  int*    cnt1  = (int*)alloc(16 * 4);
  int*    off1  = (int*)alloc(16 * 4);
  int*    mem0  = (int*)alloc((size_t)CCH * 4);
  int*    mem1  = (int*)alloc((size_t)CCH * 4);
  int*    rs0   = (int*)alloc((size_t)CCH * 8 * 4);
  int*    rs1   = (int*)alloc((size_t)CCH * 8 * 4);
  int*    rowC0 = (int*)alloc((size_t)CCH * 4);
  int*    rowC1 = (int*)alloc((size_t)CCH * 4);
  float*  sn2   = (float*)alloc((size_t)NSL * 4);
  uint4*  Bfrag0 = (uint4*)alloc((size_t)32 * 28 * 64 * 16);
  uint4*  Bfrag1 = (uint4*)alloc((size_t)8 * 28 * 64 * 16);
  float*  P8_0  = (float*)alloc((size_t)8 * CCH * 64 * 4);
  float*  P8_1  = (float*)alloc((size_t)8 * CCH * 16 * 4);

  hipMemsetAsync(concNum, 0, (80 + 2) * 4, stream);
  k_setup<<<80, 64, 0, stream>>>(im0, im1, cnt0, off0, cnt1, off1,
                                 mem0, mem1, rs0, rs1, rowC0, rowC1);
  k_brep<<<10, 256, 0, stream>>>(X, off0, off1, rs0, rs1, Bfrag0, Bfrag1);
  k_gemm_all<<<dim3(512, 8), 256, 0, stream>>>(X, rs0, rs1, Bfrag0, Bfrag1, P8_0, P8_1, sn2);
  k_fin1<<<256, 256, 0, stream>>>(P8_0, P8_1, sn2, rs0, rs1, off0, off1, rowC0, rowC1, concNum);
  k_fin2<64><<<CCH / 4, 256, 0, stream>>>(P8_0, cnt0, rowC0, concNum, 0, lossAcc, 0);
  k_fin2<16><<<CCH / 16, 256, 0, stream>>>(P8_1, cnt1, rowC1, concNum, 64, lossAcc, 1);
  k_final<<<1, 64, 0, stream>>>(lossAcc, out);
}